// Round 6
// baseline (1107.359 us; speedup 1.0000x reference)
//
#include <hip/hip_runtime.h>

#define AS1 __attribute__((address_space(1)))
#define AS3 __attribute__((address_space(3)))

typedef __bf16 bf16;
typedef unsigned char u8;
typedef __bf16 bf16x8 __attribute__((ext_vector_type(8)));
typedef __bf16 bf16x4v __attribute__((ext_vector_type(4)));
typedef float  f32x4  __attribute__((ext_vector_type(4)));

#define MFMA16(a,b,c) __builtin_amdgcn_mfma_f32_16x16x32_bf16((a),(b),(c),0,0,0)
#define MFMAF8(a,b,c) __builtin_amdgcn_mfma_f32_16x16x32_fp8_fp8((a),(b),(c),0,0,0)
#define BARX() asm volatile("s_waitcnt lgkmcnt(0)\ns_barrier" ::: "memory")
#define VMW(n) asm volatile("s_waitcnt vmcnt(" #n ")" ::: "memory")

static __device__ __forceinline__ void gll16(const bf16* src, bf16* lds) {
  __builtin_amdgcn_global_load_lds((const AS1 void*)src, (AS3 void*)lds, 16, 0, 0);
}
static __device__ __forceinline__ void gll16b(const u8* src, u8* lds) {
  __builtin_amdgcn_global_load_lds((const AS1 void*)src, (AS3 void*)lds, 16, 0, 0);
}

// ---------------- Kernel 0: weights fp32 -> bf16 ----------------
__global__ void convw_k(const float* __restrict__ s, bf16* __restrict__ d) {
  int i = (blockIdx.x * 256 + threadIdx.x) * 4;
  float4 v = *(const float4*)(s + i);
  bf16x4v o;
  o[0] = (bf16)v.x; o[1] = (bf16)v.y; o[2] = (bf16)v.z; o[3] = (bf16)v.w;
  *(bf16x4v*)(d + i) = o;
}

// ------------- Kernel 1: transpose+convert feat [B,C,4096] -> [B,4096,C] bf16 -------------
__global__ void tconv_k(const float* __restrict__ f0, const float* __restrict__ f1,
                        bf16* __restrict__ xq, bf16* __restrict__ xkv) {
  const int z = blockIdx.z;
  const int b = z & 7;
  const float* src = (z < 8) ? f0 : f1;
  bf16* dst = (z < 8) ? xq : xkv;
  const int n0 = blockIdx.x * 32, c0 = blockIdx.y * 32;
  __shared__ float tile[32][33];
  const int tx = threadIdx.x, ty = threadIdx.y;
  const size_t base = (size_t)b * 512 * 4096;
#pragma unroll
  for (int i = 0; i < 4; i++) {
    int c = ty + i * 8;
    tile[c][tx] = src[base + (size_t)(c0 + c) * 4096 + n0 + tx];
  }
  __syncthreads();
  const size_t ob = (size_t)b * 4096 * 512;
#pragma unroll
  for (int i = 0; i < 4; i++) {
    int n = ty + i * 8;
    dst[ob + (size_t)(n0 + n) * 512 + c0 + tx] = (bf16)tile[tx][n];
  }
}

// ------------- Kernel 2: generic GEMM  out[r,co] = sum_k A[r,k]*W[co,k] + bias[co] -------------
// MODE 0: out bf16 [B,4096,512] plain                  (Q)
// MODE 3: out bf16 [B,4096,512], 8-elem chunk c -> c^(row&7) within row  (K image)
// MODE 1: out fp8 e4m3 tiled [B][128 pair][co 512][32 kv], 8B-chunk G -> G^((co>>2)&3)  (V image)
// MODE 2: out fp32 transposed [B,512,4096] + residual feat0  (final)
template<int MODE>
__global__ __launch_bounds__(256) void gemm_k(const bf16* __restrict__ A, const bf16* __restrict__ W,
                                              const float* __restrict__ bias, bf16* __restrict__ outB,
                                              float* __restrict__ outF, const float* __restrict__ resid) {
  const int b = blockIdx.y;
  const int rt = blockIdx.x >> 2, ct = blockIdx.x & 3;
  const int r0 = rt * 128, c0 = ct * 128;
  const int t = threadIdx.x, w = t >> 6, l = t & 63;
  __shared__ alignas(16) bf16 As[128 * 32];
  __shared__ alignas(16) bf16 Bs[128 * 32];
  f32x4 acc[4][4];
  const f32x4 fzero = {0.f, 0.f, 0.f, 0.f};
#pragma unroll
  for (int m = 0; m < 4; m++)
#pragma unroll
    for (int n = 0; n < 4; n++) acc[m][n] = fzero;
  const bf16* Ab = A + (size_t)b * 4096 * 512 + (size_t)r0 * 512;
  const int wr = (w >> 1) * 64, wc = (w & 1) * 64;
  for (int kk = 0; kk < 16; kk++) {
    const int k0 = kk * 32;
#pragma unroll
    for (int h = 0; h < 2; h++) {
      const int rowbase = w * 32 + h * 16;
      const int row = rowbase + (l >> 2);
      const int cl = (l & 3) ^ ((row >> 1) & 3);
      gll16(Ab + (size_t)row * 512 + k0 + cl * 8, As + rowbase * 32);
      gll16(W + (size_t)(c0 + row) * 512 + k0 + cl * 8, Bs + rowbase * 32);
    }
    __syncthreads();
    bf16x8 af[4], bfr[4];
#pragma unroll
    for (int m = 0; m < 4; m++) {
      const int row = wr + m * 16 + (l & 15);
      af[m] = *(const bf16x8*)(As + row * 32 + (((l >> 4) ^ ((row >> 1) & 3)) << 3));
    }
#pragma unroll
    for (int n = 0; n < 4; n++) {
      const int row = wc + n * 16 + (l & 15);
      bfr[n] = *(const bf16x8*)(Bs + row * 32 + (((l >> 4) ^ ((row >> 1) & 3)) << 3));
    }
#pragma unroll
    for (int m = 0; m < 4; m++)
#pragma unroll
      for (int n = 0; n < 4; n++)
        acc[m][n] = MFMA16(af[m], bfr[n], acc[m][n]);
    __syncthreads();
  }
#pragma unroll
  for (int n = 0; n < 4; n++) {
    const int co = c0 + wc + n * 16 + (l & 15);
    const float bv = bias[co];
#pragma unroll
    for (int m = 0; m < 4; m++) {
      const int rb = r0 + wr + m * 16 + ((l >> 4) << 2);
      if constexpr (MODE == 0) {
#pragma unroll
        for (int i = 0; i < 4; i++)
          outB[(size_t)b * 4096 * 512 + (size_t)(rb + i) * 512 + co] = (bf16)(acc[m][n][i] + bv);
      } else if constexpr (MODE == 3) {
#pragma unroll
        for (int i = 0; i < 4; i++) {
          const int row = rb + i;
          const int colp = (((co >> 3) ^ (row & 7)) << 3) | (co & 7);
          outB[(size_t)b * 4096 * 512 + (size_t)row * 512 + colp] = (bf16)(acc[m][n][i] + bv);
        }
      } else if constexpr (MODE == 1) {
        // V image: fp8 e4m3, [B][rb>>5][co][32 kv], chunk G=(kv>>3) at pos G^((co>>2)&3), byte kv&7
        int pw = 0;
        pw = __builtin_amdgcn_cvt_pk_fp8_f32(acc[m][n][0] + bv, acc[m][n][1] + bv, pw, false);
        pw = __builtin_amdgcn_cvt_pk_fp8_f32(acc[m][n][2] + bv, acc[m][n][3] + bv, pw, true);
        const int kvin = rb & 31;
        const int pos = ((kvin >> 3) ^ ((co >> 2) & 3));
        u8* ov = (u8*)outB;
        const size_t o = (((size_t)b * 128 + (rb >> 5)) * 512 + co) * 32 + (pos << 3) + (kvin & 4);
        *(int*)(ov + o) = pw;
      } else {
        const size_t o = ((size_t)b * 512 + co) * 4096 + rb;
        float4 rv = *(const float4*)(resid + o);
        float4 ov;
        ov.x = acc[m][n][0] + bv + rv.x;
        ov.y = acc[m][n][1] + bv + rv.y;
        ov.z = acc[m][n][2] + bv + rv.z;
        ov.w = acc[m][n][3] + bv + rv.w;
        *(float4*)(outF + o) = ov;
      }
    }
  }
}

// ------------- Kernel 3: flash cross-attention, 64-q blocks, 2 blocks/CU -------------
// 8 waves = 4 pairs; pair p owns q [n0+16p,+16); wave h owns C/co half h.
// Q plain [B,4096,512]; K image MODE3; V image fp8 MODE1.
// Body T: QK sub-tiles 2T,2T+1 (16 keys each, MFMA16) -> Sx(f32 ring-4); softmax+PV(fp8) pair T-1.
__global__ __launch_bounds__(512, 4) void flash_k(const bf16* __restrict__ Q, const bf16* __restrict__ K,
                                                  const u8* __restrict__ Vt, bf16* __restrict__ ctx) {
  __shared__ alignas(16) bf16 Ks[2][16 * 512];      // 32 KB: sub-tile slots (even/odd)
  __shared__ alignas(16) u8 Vs[16384];              // 16 KB: single V pair-tile
  __shared__ alignas(16) float Sx[8][4][256];       // 32 KB: wave x ring4-slot x (16q x 16k)
  const int flat = blockIdx.x;
  const int fs = (flat & 7) * 64 + (flat >> 3);     // XCD co-location: batch b -> XCD b
  const int b = fs >> 6, n0 = (fs & 63) * 64;
  const int tid = threadIdx.x, w = tid >> 6, l = tid & 63;
  const int h = w & 1, p = w >> 1;
  const int r16 = l & 15, G = l >> 4;
  const int kxo = r16 & 7;                          // K image row-swizzle key&7
  const int sxo = (r16 >> 1) & 3;                   // Sx chunk xor

  // Q B-fragments: qf[ci] = Q[n0+16p+r16][256h + ci*32 + G*8 + j]
  bf16x8 qf[8];
  {
    const bf16* Qb = Q + ((size_t)b * 4096 + n0 + p * 16 + r16) * 512 + h * 256 + G * 8;
#pragma unroll
    for (int ci = 0; ci < 8; ci++) qf[ci] = *(const bf16x8*)(Qb + ci * 32);
  }
  f32x4 acc[16];
  const f32x4 fz = {0.f, 0.f, 0.f, 0.f};
#pragma unroll
  for (int ct = 0; ct < 16; ct++) acc[ct] = fz;
  float mrow = -1e30f, lrow = 0.f;

  const bf16* Kg = K + (size_t)b * 4096 * 512;
  const u8* Vg = Vt + (size_t)b * 128 * 16384;
  float* mySx = &Sx[w][0][0];
  float* paSx = &Sx[p * 2 + (1 - h)][0][0];

  // prologue: stage K sub-tiles 0,1 (wave w stages rows 2w,2w+1 of each)
#pragma unroll
  for (int s = 0; s < 2; s++)
#pragma unroll
    for (int jj = 0; jj < 2; jj++)
      gll16(Kg + (size_t)(s * 16 + w * 2 + jj) * 512 + l * 8, &Ks[s][0] + (w * 2 + jj) * 512);

#pragma unroll 1
  for (int T = 0; T <= 128; ++T) {
    // ---- P1: wait K(2T),K(2T+1); leave V(T-1) in flight ----
    if (T == 0 || T == 128) { VMW(0); } else { VMW(2); }
    BARX();  // BAR-A
    // ---- P2: QK for sub-tiles 2T, 2T+1 over my C-half ----
    if (T <= 127) {
#pragma unroll
      for (int s = 0; s < 2; s++) {
        const bf16* kb = &Ks[s][0] + r16 * 512;
        f32x4 sa = fz, sb = fz;
#pragma unroll
        for (int ci = 0; ci < 4; ci++) {
          const int cc0 = 32 * h + ci * 4 + G;
          const int cc1 = cc0 + 16;
          bf16x8 k0 = *(const bf16x8*)(kb + ((cc0 ^ kxo) << 3));
          bf16x8 k1 = *(const bf16x8*)(kb + ((cc1 ^ kxo) << 3));
          sa = MFMA16(k0, qf[ci], sa);
          sb = MFMA16(k1, qf[ci + 4], sb);
        }
        f32x4 sv = sa + sb;
        float* sl = mySx + ((2 * T + s) & 3) * 256;
        float4 v4 = {sv[0], sv[1], sv[2], sv[3]};
        *(float4*)((char*)sl + r16 * 64 + ((G ^ sxo) << 4)) = v4;
      }
    }
    // ---- P3: drain V(T-1); make all waves' V + Sx writes visible ----
    VMW(0);
    BARX();  // BAR-B
    // ---- P4: stage K(2T+2),K(2T+3) ----
    if (T <= 126) {
#pragma unroll
      for (int s = 0; s < 2; s++)
#pragma unroll
        for (int jj = 0; jj < 2; jj++)
          gll16(Kg + (size_t)((2 * T + 2 + s) * 16 + w * 2 + jj) * 512 + l * 8,
                &Ks[s][0] + (w * 2 + jj) * 512);
    }
    // ---- P5: softmax + PV for pair T-1 ----
    if (T >= 1) {
      const int sb2 = G >> 1;                           // my kv-set's sub-tile
      const int slot = (2 * (T - 1) + sb2) & 3;
      const int c0 = 2 * (G & 1);
      const char* mo = (const char*)(mySx + slot * 256) + r16 * 64;
      const char* po = (const char*)(paSx + slot * 256) + r16 * 64;
      float4 eo0 = *(const float4*)(mo + ((c0 ^ sxo) << 4));
      float4 eo1 = *(const float4*)(mo + (((c0 + 1) ^ sxo) << 4));
      float4 ep0 = *(const float4*)(po + ((c0 ^ sxo) << 4));
      float4 ep1 = *(const float4*)(po + (((c0 + 1) ^ sxo) << 4));
      float e0 = eo0.x + ep0.x, e1 = eo0.y + ep0.y, e2 = eo0.z + ep0.z, e3 = eo0.w + ep0.w;
      float e4 = eo1.x + ep1.x, e5 = eo1.y + ep1.y, e6 = eo1.z + ep1.z, e7 = eo1.w + ep1.w;
      float pmax = fmaxf(fmaxf(fmaxf(e0, e1), fmaxf(e2, e3)),
                         fmaxf(fmaxf(e4, e5), fmaxf(e6, e7)));
      pmax = fmaxf(pmax, __shfl_xor(pmax, 16));
      pmax = fmaxf(pmax, __shfl_xor(pmax, 32));
      if (!__all(pmax <= mrow + 5.0f)) {               // THR=5: P <= e^5=148 < fp8 max 448
        const float mnew = fmaxf(mrow, pmax);
        const float scl = __expf(mrow - mnew);
        mrow = mnew;
        lrow *= scl;
        const int sclI = __float_as_int(scl);
        f32x4 s4;
#pragma unroll
        for (int r = 0; r < 4; r++)
          s4[r] = __int_as_float(__builtin_amdgcn_ds_bpermute(((G << 2) + r) << 2, sclI));
#pragma unroll
        for (int ct = 0; ct < 16; ct++) acc[ct] *= s4;
      }
      e0 = __expf(e0 - mrow); e1 = __expf(e1 - mrow); e2 = __expf(e2 - mrow); e3 = __expf(e3 - mrow);
      e4 = __expf(e4 - mrow); e5 = __expf(e5 - mrow); e6 = __expf(e6 - mrow); e7 = __expf(e7 - mrow);
      float rs = ((e0 + e1) + (e2 + e3)) + ((e4 + e5) + (e6 + e7));
      rs += __shfl_xor(rs, 16);
      rs += __shfl_xor(rs, 32);
      lrow += rs;
      // pack P -> fp8 A-fragment (bytes in kv order G*8+j)
      int u0 = 0, u1 = 0;
      u0 = __builtin_amdgcn_cvt_pk_fp8_f32(e0, e1, u0, false);
      u0 = __builtin_amdgcn_cvt_pk_fp8_f32(e2, e3, u0, true);
      u1 = __builtin_amdgcn_cvt_pk_fp8_f32(e4, e5, u1, false);
      u1 = __builtin_amdgcn_cvt_pk_fp8_f32(e6, e7, u1, true);
      const long pf = (long)(((unsigned long long)(unsigned)u1 << 32) | (unsigned)u0);
      __builtin_amdgcn_s_setprio(1);
#pragma unroll
      for (int ct = 0; ct < 16; ct++) {
        const int co = h * 256 + ct * 16 + r16;
        const long vf = *(const long*)(Vs + co * 32 + ((G ^ ((co >> 2) & 3)) << 3));
        acc[ct] = MFMAF8(pf, vf, acc[ct]);
      }
      __builtin_amdgcn_s_setprio(0);
    }
    BARX();  // BAR-C: PV's Vs reads done
    // ---- P6: stage V(T) into single buffer ----
    if (T <= 127) {
#pragma unroll
      for (int jj = 0; jj < 2; jj++)
        gll16b(Vg + (size_t)T * 16384 + (w * 2 + jj) * 1024 + l * 16, Vs + (w * 2 + jj) * 1024);
    }
  }

  // ---- epilogue: ctx = acc / lrow * C^-0.5 ----
  const float inv = 0.04419417382415922f / lrow;
  const int invI = __float_as_int(inv);
  float fin[4];
#pragma unroll
  for (int r = 0; r < 4; r++)
    fin[r] = __int_as_float(__builtin_amdgcn_ds_bpermute(((G << 2) + r) << 2, invI));
  const size_t ob = (size_t)b * 4096 * 512;
#pragma unroll
  for (int ct = 0; ct < 16; ct++) {
    const int co = h * 256 + ct * 16 + r16;
#pragma unroll
    for (int r = 0; r < 4; r++) {
      const size_t q = n0 + p * 16 + (G << 2) + r;
      ctx[ob + q * 512 + co] = (bf16)(acc[ct][r] * fin[r]);
    }
  }
}

extern "C" void kernel_launch(void* const* d_in, const int* in_sizes, int n_in,
                              void* d_out, int out_size, void* d_ws, size_t ws_size,
                              hipStream_t stream) {
  const float* feat0 = (const float*)d_in[0];
  const float* feat1 = (const float*)d_in[1];
  const float* Wq = (const float*)d_in[2];
  const float* bq = (const float*)d_in[3];
  const float* Wk = (const float*)d_in[4];
  const float* bk = (const float*)d_in[5];
  const float* Wv = (const float*)d_in[6];
  const float* bv = (const float*)d_in[7];
  const float* Wo = (const float*)d_in[8];
  const float* bo = (const float*)d_in[9];
  float* out = (float*)d_out;

  char* ws = (char*)d_ws;
  bf16* Wqb = (bf16*)(ws);
  bf16* Wkb = (bf16*)(ws + (1 << 19));
  bf16* Wvb = (bf16*)(ws + 2 * (size_t)(1 << 19));
  bf16* Wob = (bf16*)(ws + 3 * (size_t)(1 << 19));
  const size_t TEN = (size_t)8 * 4096 * 512 * 2;  // 33.55 MB per bf16 tensor
  char* p = ws + 4 * (size_t)(1 << 19);
  bf16* Xq  = (bf16*)(p);
  bf16* Xkv = (bf16*)(p + TEN);
  bf16* Qb  = (bf16*)(p + 2 * TEN);
  bf16* Kb  = (bf16*)(p + 3 * TEN);
  bf16* Vtb = (bf16*)(p + 4 * TEN);   // fp8 image (uses half the slot)
  bf16* ctx = Xq;  // Xq dead after Q projection

  convw_k<<<256, 256, 0, stream>>>(Wq, Wqb);
  convw_k<<<256, 256, 0, stream>>>(Wk, Wkb);
  convw_k<<<256, 256, 0, stream>>>(Wv, Wvb);
  convw_k<<<256, 256, 0, stream>>>(Wo, Wob);
  tconv_k<<<dim3(128, 16, 16), dim3(32, 8), 0, stream>>>(feat0, feat1, Xq, Xkv);
  gemm_k<0><<<dim3(128, 8), 256, 0, stream>>>(Xq,  Wqb, bq, Qb,  nullptr, nullptr);
  gemm_k<3><<<dim3(128, 8), 256, 0, stream>>>(Xkv, Wkb, bk, Kb,  nullptr, nullptr);
  gemm_k<1><<<dim3(128, 8), 256, 0, stream>>>(Xkv, Wvb, bv, Vtb, nullptr, nullptr);
  flash_k<<<dim3(512), dim3(512), 0, stream>>>(Qb, Kb, (const u8*)Vtb, ctx);
  gemm_k<2><<<dim3(128, 8), 256, 0, stream>>>(ctx, Wob, bo, nullptr, out, feat0);
}